// Round 3
// baseline (9162.460 us; speedup 1.0000x reference)
//
#include <hip/hip_runtime.h>

typedef __bf16 bf16x8 __attribute__((ext_vector_type(8)));
typedef unsigned short ushort8_t __attribute__((ext_vector_type(8)));
typedef float f32x4 __attribute__((ext_vector_type(4)));
typedef unsigned int uint4_t __attribute__((ext_vector_type(4)));

#define MFMA16(a,b,c) __builtin_amdgcn_mfma_f32_16x16x32_bf16((a),(b),(c),0,0,0)

// B=512 T=1024 Din=128 H=512 Dout=128
// 64 blocks x 256 thr (4 waves). Pair (g, g+32): role = bid>>5 owns H-cols
// [role*256, role*256+256). ALL weights register-resident (320 VGPR/lane).
// Per-step 8KB h-half exchange via ws mailboxes (parity double-buffered,
// agent-scope atomics -> correct regardless of XCD placement).
// ws: [0,2048)        bias f32[512] = bx+bh
//     [2048,10240)    flags, u32 each in own 64B line, idx=((g*2+role)*2+par)
//     [16384,+128*8K) mailboxes 8KB each, same idx; layout [256 col][16 row] bf16

__device__ __forceinline__ unsigned short f2bf(float f) {
  unsigned int u = __float_as_uint(f);
  u += 0x7FFFu + ((u >> 16) & 1u);  // RTNE
  return (unsigned short)(u >> 16);
}
__device__ __forceinline__ bf16x8 pack8v(float4 a, float4 b) {
  ushort8_t u;
  u[0] = f2bf(a.x); u[1] = f2bf(a.y); u[2] = f2bf(a.z); u[3] = f2bf(a.w);
  u[4] = f2bf(b.x); u[5] = f2bf(b.y); u[6] = f2bf(b.z); u[7] = f2bf(b.w);
  return __builtin_bit_cast(bf16x8, u);
}
__device__ __forceinline__ bf16x8 pack8p(const float* __restrict__ s) {
  float4 a = *(const float4*)s, b = *(const float4*)(s + 4);
  return pack8v(a, b);
}

__global__ void rnn_prep(const float* __restrict__ bx, const float* __restrict__ bh,
                         void* __restrict__ ws) {
  int tid = threadIdx.x;  // 512 threads
  ((float*)ws)[tid] = bx[tid] + bh[tid];
  if (tid < 128) *(unsigned*)((char*)ws + 2048 + tid * 64) = 0u;
}

__global__ __launch_bounds__(256, 1) void rnn_scan(
    const float* __restrict__ x, const float* __restrict__ Wx,
    const float* __restrict__ Wh, const float* __restrict__ Wy,
    const float* __restrict__ by, void* __restrict__ ws,
    float* __restrict__ out) {
  __shared__ alignas(16) char h_lds[32768];  // 2 x [16 rows][512 cols] bf16, swizzled
  __shared__ alignas(16) char x_lds[8192];   // 2 x [16 rows][128 k]   bf16, swizzled

  const int tid = threadIdx.x;
  const int w = tid >> 6, l = tid & 63, m = l & 15, kg = l >> 4;
  const int g = blockIdx.x & 31, role = blockIdx.x >> 5;
  const int bb = g << 4;
  const int pbase = (1 - role) << 8;
  const int sw = (m & 7) << 4;

  char* wsb = (char*)ws;
  const float* biasp = (const float*)wsb;

  // ---- register-resident weights: 20 k-tiles x 4 col-frags = 320 VGPRs ----
  bf16x8 bw[20][4];
  float bv[4];
#pragma unroll
  for (int nt = 0; nt < 4; ++nt) {
    const int cn = role * 256 + w * 64 + nt * 16 + m;
    bv[nt] = biasp[cn];
#pragma unroll
    for (int kt = 0; kt < 16; ++kt)
      bw[kt][nt] = pack8p(Wh + (size_t)cn * 512 + kt * 32 + kg * 8);
#pragma unroll
    for (int kx = 0; kx < 4; ++kx)
      bw[16 + kx][nt] = pack8p(Wx + (size_t)cn * 128 + kx * 32 + kg * 8);
  }

  // ---- A-frag LDS read offsets (swizzle: F(r,k)=r*RS+((k>>6)<<7)+((2*(k&63))^((r&7)<<4)))
  int aoff_h[16], aoff_x[4];
#pragma unroll
  for (int kt = 0; kt < 16; ++kt)
    aoff_h[kt] = m * 1024 + ((kt >> 1) << 7) + ((((kt & 1) << 6) + (kg << 4)) ^ sw);
#pragma unroll
  for (int kx = 0; kx < 4; ++kx)
    aoff_x[kx] = m * 256 + ((kx >> 1) << 7) + ((((kx & 1) << 6) + (kg << 4)) ^ sw);

  // ---- x staging: thread -> (row, 8 k) ----
  const int srow = tid >> 4, sk0 = (tid & 15) << 3;
  const float* xsrc = x + (size_t)(bb + srow) * 1024 * 128 + sk0;
  const int xw_off = srow * 256 + ((sk0 >> 6) << 7) + (((sk0 & 63) << 1) ^ ((srow & 7) << 4));

  // ---- mailbox / flag pointers (scalar, no runtime-indexed arrays) ----
  char* const mail_my0 = wsb + 16384 + (size_t)((g * 2 + role) * 2 + 0) * 8192;
  char* const mail_my1 = wsb + 16384 + (size_t)((g * 2 + role) * 2 + 1) * 8192;
  const char* const mail_pt0 = wsb + 16384 + (size_t)((g * 2 + (1 - role)) * 2 + 0) * 8192;
  const char* const mail_pt1 = wsb + 16384 + (size_t)((g * 2 + (1 - role)) * 2 + 1) * 8192;
  unsigned* const flag_my0 = (unsigned*)(wsb + 2048 + ((g * 2 + role) * 2 + 0) * 64);
  unsigned* const flag_my1 = (unsigned*)(wsb + 2048 + ((g * 2 + role) * 2 + 1) * 64);
  const unsigned* const flag_pt0 = (const unsigned*)(wsb + 2048 + ((g * 2 + (1 - role)) * 2 + 0) * 64);
  const unsigned* const flag_pt1 = (const unsigned*)(wsb + 2048 + ((g * 2 + (1 - role)) * 2 + 1) * 64);

  // ---- init: h(0)=0 (full 16KB buffer 0), stage x(0) ----
  {
    uint4_t z = {0, 0, 0, 0};
#pragma unroll
    for (int j = 0; j < 4; ++j) *(uint4_t*)(h_lds + tid * 64 + j * 16) = z;
    float4 xa = *(const float4*)(xsrc);
    float4 xb2 = *(const float4*)(xsrc + 4);
    *(bf16x8*)(x_lds + xw_off) = pack8v(xa, xb2);
  }
  __syncthreads();

  for (int t = 0; t < 1024; ++t) {
    const int cur = t & 1;
    const int par = (t + 1) & 1;
    const char* hb = h_lds + (cur << 14);
    const char* xbuf = x_lds + (cur << 12);
    char* hn = h_lds + ((cur ^ 1) << 14);
    char* xn = x_lds + ((cur ^ 1) << 12);
    char* mm = par ? mail_my1 : mail_my0;
    const char* mp = par ? mail_pt1 : mail_pt0;
    unsigned* fm = par ? flag_my1 : flag_my0;
    const unsigned* fp = par ? flag_pt1 : flag_pt0;

    // prefetch x(t+1)
    const int tt = (t < 1023) ? t + 1 : 1023;
    float4 xa = *(const float4*)(xsrc + (size_t)tt * 128);
    float4 xb2 = *(const float4*)(xsrc + (size_t)tt * 128 + 4);

    f32x4 a0 = {0, 0, 0, 0}, a1 = {0, 0, 0, 0}, a2 = {0, 0, 0, 0}, a3 = {0, 0, 0, 0};
#pragma unroll
    for (int kt = 0; kt < 16; ++kt) {
      bf16x8 a = *(const bf16x8*)(hb + aoff_h[kt]);
      a0 = MFMA16(a, bw[kt][0], a0);
      a1 = MFMA16(a, bw[kt][1], a1);
      a2 = MFMA16(a, bw[kt][2], a2);
      a3 = MFMA16(a, bw[kt][3], a3);
    }
#pragma unroll
    for (int kx = 0; kx < 4; ++kx) {
      bf16x8 a = *(const bf16x8*)(xbuf + aoff_x[kx]);
      a0 = MFMA16(a, bw[16 + kx][0], a0);
      a1 = MFMA16(a, bw[16 + kx][1], a1);
      a2 = MFMA16(a, bw[16 + kx][2], a2);
      a3 = MFMA16(a, bw[16 + kx][3], a3);
    }

    // tanh -> bf16, packed as u32 row-pairs
    unsigned pk[4][2];
#pragma unroll
    for (int ct = 0; ct < 4; ++ct) {
      const f32x4 av = ct == 0 ? a0 : ct == 1 ? a1 : ct == 2 ? a2 : a3;
      unsigned short hv[4];
#pragma unroll
      for (int i = 0; i < 4; ++i) {
        float pre = av[i] + bv[ct];
        float e = __expf(2.f * pre);
        hv[i] = f2bf(1.f - 2.f / (e + 1.f));
      }
      pk[ct][0] = (unsigned)hv[0] | ((unsigned)hv[1] << 16);
      pk[ct][1] = (unsigned)hv[2] | ((unsigned)hv[3] << 16);
    }

    // mailbox: [col][row] bf16; thread writes 4 cols x (4 rows packed as 2 u32)
#pragma unroll
    for (int ct = 0; ct < 4; ++ct) {
      unsigned* dst = (unsigned*)(mm + (w * 64 + ct * 16 + m) * 32 + kg * 8);
      __hip_atomic_store(dst, pk[ct][0], __ATOMIC_RELAXED, __HIP_MEMORY_SCOPE_AGENT);
      __hip_atomic_store(dst + 1, pk[ct][1], __ATOMIC_RELAXED, __HIP_MEMORY_SCOPE_AGENT);
    }
    __syncthreads();  // drains vmcnt(0): all mailbox atomics complete
    if (tid == 0) {
      __threadfence();
      __hip_atomic_store(fm, (unsigned)(t + 1), __ATOMIC_RELEASE, __HIP_MEMORY_SCOPE_AGENT);
    }

    // own-half h(t+1) into LDS[nxt]
#pragma unroll
    for (int ct = 0; ct < 4; ++ct) {
#pragma unroll
      for (int i = 0; i < 4; ++i) {
        const int r = kg * 4 + i;
        const int off = r * 1024 + ((role * 4 + w) << 7) + ((ct * 32 + 2 * m) ^ ((r & 7) << 4));
        const unsigned v = (i & 1) ? (pk[ct][i >> 1] >> 16) : (pk[ct][i >> 1] & 0xffffu);
        *(unsigned short*)(hn + off) = (unsigned short)v;
      }
    }
    // x(t+1) into LDS[nxt]
    *(bf16x8*)(xn + xw_off) = pack8v(xa, xb2);

    // wait for partner half (lane 0 of each wave polls; rest wait at reconvergence)
    if (l == 0) {
      while (__hip_atomic_load(fp, __ATOMIC_RELAXED, __HIP_MEMORY_SCOPE_AGENT) < (unsigned)(t + 1)) {}
    }
    __threadfence();  // acquire

    // stage partner half: thread owns one col
    {
      const unsigned* src = (const unsigned*)(mp + tid * 32);
      unsigned d[8];
#pragma unroll
      for (int j = 0; j < 8; ++j)
        d[j] = __hip_atomic_load(src + j, __ATOMIC_RELAXED, __HIP_MEMORY_SCOPE_AGENT);
      const int k = pbase + tid;
      const int kb = ((k >> 6) << 7);
      const int k2 = 2 * (k & 63);
#pragma unroll
      for (int j = 0; j < 8; ++j) {
#pragma unroll
        for (int h2 = 0; h2 < 2; ++h2) {
          const int r = 2 * j + h2;
          const int off = r * 1024 + kb + (k2 ^ ((r & 7) << 4));
          const unsigned short v = h2 ? (unsigned short)(d[j] >> 16) : (unsigned short)(d[j] & 0xffffu);
          *(unsigned short*)(hn + off) = v;
        }
      }
    }
    __syncthreads();
  }

  // ---- epilogue: role 0 computes y = h(1024) @ Wy^T + by (h(1024) in buffer 0) ----
  if (role == 0) {
    f32x4 y0 = {0, 0, 0, 0}, y1 = {0, 0, 0, 0};
    const int c0 = w * 32 + m, c1 = w * 32 + 16 + m;
#pragma unroll
    for (int kt = 0; kt < 16; ++kt) {
      bf16x8 a = *(const bf16x8*)(h_lds + aoff_h[kt]);
      y0 = MFMA16(a, pack8p(Wy + (size_t)c0 * 512 + kt * 32 + kg * 8), y0);
      y1 = MFMA16(a, pack8p(Wy + (size_t)c1 * 512 + kt * 32 + kg * 8), y1);
    }
    const float b0 = by[c0], b1 = by[c1];
#pragma unroll
    for (int i = 0; i < 4; ++i) {
      const int r = kg * 4 + i;
      out[(size_t)(bb + r) * 128 + c0] = y0[i] + b0;
      out[(size_t)(bb + r) * 128 + c1] = y1[i] + b1;
    }
  }
}

extern "C" void kernel_launch(void* const* d_in, const int* in_sizes, int n_in,
                              void* d_out, int out_size, void* d_ws, size_t ws_size,
                              hipStream_t stream) {
  const float* x  = (const float*)d_in[0];
  const float* Wx = (const float*)d_in[1];
  const float* bx = (const float*)d_in[2];
  const float* Wh = (const float*)d_in[3];
  const float* bh = (const float*)d_in[4];
  const float* Wy = (const float*)d_in[5];
  const float* by = (const float*)d_in[6];

  rnn_prep<<<1, 512, 0, stream>>>(bx, bh, d_ws);
  rnn_scan<<<64, 256, 0, stream>>>(x, Wx, Wh, Wy, by, d_ws, (float*)d_out);
}

// Round 4
// 5226.168 us; speedup vs baseline: 1.7532x; 1.7532x over previous
//
#include <hip/hip_runtime.h>

typedef __bf16 bf16x8 __attribute__((ext_vector_type(8)));
typedef unsigned short ushort8_t __attribute__((ext_vector_type(8)));
typedef float f32x4 __attribute__((ext_vector_type(4)));
typedef unsigned int uint4_t __attribute__((ext_vector_type(4)));

#define MFMA16(a,b,c) __builtin_amdgcn_mfma_f32_16x16x32_bf16((a),(b),(c),0,0,0)

// B=512 T=1024 Din=128 H=512 Dout=128
// Plan:
//  1) rnn_prep: pack Wh k-tiles 12..15 as MFMA B-frags into ws[0,128K) + bias(bx+bh) at ws+128K.
//  2) xp_gemm: xp[b,t,:] = x[b,t,:]@Wx^T + bias, stored bf16 in g_xp in SCAN-READY layout:
//     g_xp[((g*1024+t)*256 + tid)*32 + cf*4 + i]  (64B per scan-thread per step, coalesced).
//  3) rnn_scan: 32 blocks x 256 thr (4 waves, 1 wave/SIMD, 512 VGPR budget).
//     Wave w owns cols [w*128, w*128+128). Wh kt0..11 in VGPRs, kt12..14 in LDS,
//     kt15 loop-invariant (compiler hoists to regs). h double-buffered in LDS (32KB).
//     Per-step: acc=xp(t) [4x dwordx4]; 128 MFMA; tanh; h-write; 1 barrier.

__device__ unsigned short g_xp[(size_t)32 * 1024 * 256 * 32];  // 512MB bf16

__device__ __forceinline__ unsigned short f2bf(float f) {
  unsigned int u = __float_as_uint(f);
  u += 0x7FFFu + ((u >> 16) & 1u);  // RTNE
  return (unsigned short)(u >> 16);
}
__device__ __forceinline__ bf16x8 pack8v(float4 a, float4 b) {
  ushort8_t u;
  u[0] = f2bf(a.x); u[1] = f2bf(a.y); u[2] = f2bf(a.z); u[3] = f2bf(a.w);
  u[4] = f2bf(b.x); u[5] = f2bf(b.y); u[6] = f2bf(b.z); u[7] = f2bf(b.w);
  return __builtin_bit_cast(bf16x8, u);
}
__device__ __forceinline__ bf16x8 pack8p(const float* __restrict__ s) {
  return pack8v(*(const float4*)s, *(const float4*)(s + 4));
}

// ---- prep: pack Wh kt12..15 B-frags (128KB) + bias into ws ----------------
__global__ void rnn_prep(const float* __restrict__ Wh, const float* __restrict__ bx,
                         const float* __restrict__ bh, void* __restrict__ ws) {
  int gid = blockIdx.x * 256 + threadIdx.x;
  if (blockIdx.x < 32) {
    // frag f = ktl*32 + w*8 + cf   (ktl 0..3 -> kt=12+ktl), lane l
    int l = gid & 63, f = gid >> 6;
    int ktl = f >> 5, wcf = f & 31;
    int c = (wcf >> 3) * 128 + (wcf & 7) * 16 + (l & 15);
    int k = (12 + ktl) * 32 + (l >> 4) * 8;
    bf16x8 v = pack8p(Wh + (size_t)c * 512 + k);
    ((ushort8_t*)ws)[gid] = __builtin_bit_cast(ushort8_t, v);
  } else {
    int i = threadIdx.x * 2;
    float* bias = (float*)((char*)ws + 131072);
    bias[i] = bx[i] + bh[i];
    bias[i + 1] = bx[i + 1] + bh[i + 1];
  }
}

// ---- xp precompute: 2048 blocks (g 0..31, tc 0..63), 256 thr --------------
__global__ __launch_bounds__(256) void xp_gemm(const float* __restrict__ x,
                                               const float* __restrict__ Wx,
                                               const void* __restrict__ ws) {
  __shared__ alignas(16) char xs[65536];  // 16 t x [16 row][128 k] bf16, swizzled
  const int tid = threadIdx.x;
  const int w = tid >> 6, l = tid & 63, m = l & 15, kg = l >> 4;
  const int g = blockIdx.x & 31, tc = blockIdx.x >> 5;
  const int bb = g << 4, t0 = tc << 4;
  const int sw = (m & 7) << 4;

  // B-frags (Wx) + bias
  bf16x8 bwx[4][8];
  float bias[8];
  const float* biasp = (const float*)((const char*)ws + 131072);
#pragma unroll
  for (int cf = 0; cf < 8; ++cf) {
    const int c = w * 128 + cf * 16 + m;
    bias[cf] = biasp[c];
#pragma unroll
    for (int kt = 0; kt < 4; ++kt)
      bwx[kt][cf] = pack8p(Wx + (size_t)c * 128 + kt * 32 + kg * 8);
  }

  // stage x slab: rows (b=16) x (t=16) x 128 k f32 -> bf16 LDS
#pragma unroll
  for (int pass = 0; pass < 8; ++pass) {
    const int row = pass * 32 + (tid >> 3);
    const int mr = row >> 4, tr = row & 15;
    const float* src = x + ((size_t)(bb + mr) * 1024 + t0 + tr) * 128 + (tid & 7) * 16;
    const int wbase = tr * 4096 + mr * 256;
    const int swr = (mr & 7) << 4;
#pragma unroll
    for (int j = 0; j < 4; ++j) {
      float4 v = *(const float4*)(src + j * 4);
      unsigned short h0 = f2bf(v.x), h1 = f2bf(v.y), h2 = f2bf(v.z), h3 = f2bf(v.w);
      unsigned lo = (unsigned)h0 | ((unsigned)h1 << 16);
      unsigned hi = (unsigned)h2 | ((unsigned)h3 << 16);
      unsigned* dst = (unsigned*)(xs + wbase + (((tid & 7) * 32 + j * 8) ^ swr));
      dst[0] = lo; dst[1] = hi;
    }
  }
  __syncthreads();

  const int xE = m * 256 + (((kg << 4)) ^ (sw & 48)) + (sw & 64);
  const int xO = m * 256 + (((kg << 4)) ^ (sw & 48)) + (64 ^ (sw & 64));

  for (int t = 0; t < 16; ++t) {
    f32x4 acc[8];
#pragma unroll
    for (int cf = 0; cf < 8; ++cf) acc[cf] = (f32x4){0.f, 0.f, 0.f, 0.f};
#pragma unroll
    for (int kt = 0; kt < 4; ++kt) {
      bf16x8 a = *(const bf16x8*)(xs + t * 4096 + ((kt >> 1) << 7) + ((kt & 1) ? xO : xE));
#pragma unroll
      for (int cf = 0; cf < 8; ++cf) acc[cf] = MFMA16(a, bwx[kt][cf], acc[cf]);
    }
    // write 32 bf16 (cf-major, i-minor) as 4 dwordx4, per-thread 64B contiguous
    unsigned dw[16];
#pragma unroll
    for (int cf = 0; cf < 8; ++cf) {
      float p0 = acc[cf][0] + bias[cf], p1 = acc[cf][1] + bias[cf];
      float p2 = acc[cf][2] + bias[cf], p3 = acc[cf][3] + bias[cf];
      dw[cf * 2]     = (unsigned)f2bf(p0) | ((unsigned)f2bf(p1) << 16);
      dw[cf * 2 + 1] = (unsigned)f2bf(p2) | ((unsigned)f2bf(p3) << 16);
    }
    uint4_t* dst = (uint4_t*)(g_xp + ((size_t)((g * 1024) + (t0 + t)) * 256 + tid) * 32);
#pragma unroll
    for (int j = 0; j < 4; ++j)
      dst[j] = (uint4_t){dw[4 * j], dw[4 * j + 1], dw[4 * j + 2], dw[4 * j + 3]};
  }
}

// ---- scan: 32 blocks x 256 thr ---------------------------------------------
__global__ __launch_bounds__(256, 1) void rnn_scan(
    const float* __restrict__ Wh, const float* __restrict__ Wy,
    const float* __restrict__ by, const void* __restrict__ ws,
    float* __restrict__ out) {
  __shared__ alignas(16) char h_lds[32768];   // 2 x [16 row][512 c] bf16, swizzled
  __shared__ alignas(16) char wh_lds[98304];  // Wh kt12..14 frags, linear

  const int tid = threadIdx.x;
  const int w = tid >> 6, l = tid & 63, m = l & 15, kg = l >> 4;
  const int g = blockIdx.x, bb = g << 4;
  const int sw = (m & 7) << 4;

  // stage wh_lds (96KB) from ws
#pragma unroll
  for (int j = 0; j < 24; ++j) {
    const int off = (j * 256 + tid) * 16;
    *(uint4_t*)(wh_lds + off) = *(const uint4_t*)((const char*)ws + off);
  }

  // RF weights kt0..11 (384 VGPR)
  bf16x8 bw[12][8];
#pragma unroll
  for (int cf = 0; cf < 8; ++cf) {
    const int c = w * 128 + cf * 16 + m;
#pragma unroll
    for (int kt = 0; kt < 12; ++kt)
      bw[kt][cf] = pack8p(Wh + (size_t)c * 512 + kt * 32 + kg * 8);
  }

  // kt15 frags: loop-invariant loads from ws (compiler hoists to 32 regs)
  const char* wsk15 = (const char*)ws + 98304 + (w * 8) * 1024 + l * 16;
  // wh_lds frag base (per wave)
  const char* whb = wh_lds + (w * 8) * 1024 + l * 16;

  // h A-read bases
  const int hE = m * 1024 + ((kg << 4) ^ (sw & 48)) + (sw & 64);
  const int hO = m * 1024 + ((kg << 4) ^ (sw & 48)) + (64 ^ (sw & 64));

  // h write constants per cf
  int cblk[8], ca2[8];
#pragma unroll
  for (int cf = 0; cf < 8; ++cf) {
    const int c = w * 128 + cf * 16 + m;
    cblk[cf] = (c >> 6) << 7;
    ca2[cf] = 2 * (c & 63);
  }

  // zero h buffer 0
  {
    uint4_t z = {0, 0, 0, 0};
#pragma unroll
    for (int j = 0; j < 4; ++j) *(uint4_t*)(h_lds + tid * 64 + j * 16) = z;
  }

  const char* xpb = (const char*)(g_xp + ((size_t)g * 1024 * 256 + tid) * 32);
  uint4_t xq0, xq1, xq2, xq3;
  {
    const uint4_t* p = (const uint4_t*)xpb;
    xq0 = p[0]; xq1 = p[1]; xq2 = p[2]; xq3 = p[3];
  }
  __syncthreads();

  for (int t = 0; t < 1024; ++t) {
    const int cur = t & 1;
    const char* hb = h_lds + (cur << 14);
    char* hn = h_lds + ((cur ^ 1) << 14);

    // prefetch xp(t+1)
    const int tn = (t < 1023) ? t + 1 : 1023;
    const uint4_t* pn = (const uint4_t*)(xpb + (size_t)tn * 16384);
    uint4_t nq0 = pn[0], nq1 = pn[1], nq2 = pn[2], nq3 = pn[3];

    // acc init from xp (bias already included)
    f32x4 acc[8];
#pragma unroll
    for (int cf = 0; cf < 8; ++cf) {
      const uint4_t q = (cf < 2) ? xq0 : (cf < 4) ? xq1 : (cf < 6) ? xq2 : xq3;
      const unsigned dlo = q[(cf & 1) * 2], dhi = q[(cf & 1) * 2 + 1];
      acc[cf][0] = __uint_as_float(dlo << 16);
      acc[cf][1] = __uint_as_float(dlo & 0xffff0000u);
      acc[cf][2] = __uint_as_float(dhi << 16);
      acc[cf][3] = __uint_as_float(dhi & 0xffff0000u);
    }

    // Wh: kt0..11 from RF
#pragma unroll
    for (int kt = 0; kt < 12; ++kt) {
      bf16x8 a = *(const bf16x8*)(hb + ((kt >> 1) << 7) + ((kt & 1) ? hO : hE));
#pragma unroll
      for (int cf = 0; cf < 8; ++cf) acc[cf] = MFMA16(a, bw[kt][cf], acc[cf]);
    }
    // kt12..14 from LDS
#pragma unroll
    for (int ktl = 0; ktl < 3; ++ktl) {
      const int kt = 12 + ktl;
      bf16x8 a = *(const bf16x8*)(hb + ((kt >> 1) << 7) + ((kt & 1) ? hO : hE));
#pragma unroll
      for (int cf = 0; cf < 8; ++cf) {
        bf16x8 b = *(const bf16x8*)(whb + ktl * 32768 + cf * 1024);
        acc[cf] = MFMA16(a, b, acc[cf]);
      }
    }
    // kt15 (hoisted loop-invariant loads)
    {
      bf16x8 a = *(const bf16x8*)(hb + (7 << 7) + hO);
#pragma unroll
      for (int cf = 0; cf < 8; ++cf) {
        bf16x8 b = *(const bf16x8*)(wsk15 + cf * 1024);
        acc[cf] = MFMA16(a, b, acc[cf]);
      }
    }

    // tanh -> bf16 -> h_lds[nxt]
#pragma unroll
    for (int cf = 0; cf < 8; ++cf) {
#pragma unroll
      for (int i = 0; i < 4; ++i) {
        const int r = kg * 4 + i;
        float e = __expf(2.f * acc[cf][i]);
        unsigned short hv = f2bf(1.f - 2.f / (e + 1.f));
        *(unsigned short*)(hn + r * 1024 + cblk[cf] + (ca2[cf] ^ ((r & 7) << 4))) = hv;
      }
    }
    __syncthreads();
    xq0 = nq0; xq1 = nq1; xq2 = nq2; xq3 = nq3;
  }

  // epilogue: y = h(1024)@Wy^T + by  (h(1024) in buffer 0; Dout=128 -> 32 c/wave)
  f32x4 y0 = {0, 0, 0, 0}, y1 = {0, 0, 0, 0};
  const int c0 = w * 32 + m, c1 = w * 32 + 16 + m;
#pragma unroll
  for (int kt = 0; kt < 16; ++kt) {
    bf16x8 a = *(const bf16x8*)(h_lds + ((kt >> 1) << 7) + ((kt & 1) ? hO : hE));
    y0 = MFMA16(a, pack8p(Wy + (size_t)c0 * 512 + kt * 32 + kg * 8), y0);
    y1 = MFMA16(a, pack8p(Wy + (size_t)c1 * 512 + kt * 32 + kg * 8), y1);
  }
  const float b0 = by[c0], b1 = by[c1];
#pragma unroll
  for (int i = 0; i < 4; ++i) {
    const int r = kg * 4 + i;
    out[(size_t)(bb + r) * 128 + c0] = y0[i] + b0;
    out[(size_t)(bb + r) * 128 + c1] = y1[i] + b1;
  }
}

extern "C" void kernel_launch(void* const* d_in, const int* in_sizes, int n_in,
                              void* d_out, int out_size, void* d_ws, size_t ws_size,
                              hipStream_t stream) {
  const float* x  = (const float*)d_in[0];
  const float* Wx = (const float*)d_in[1];
  const float* bx = (const float*)d_in[2];
  const float* Wh = (const float*)d_in[3];
  const float* bh = (const float*)d_in[4];
  const float* Wy = (const float*)d_in[5];
  const float* by = (const float*)d_in[6];

  rnn_prep<<<33, 256, 0, stream>>>(Wh, bx, bh, d_ws);
  xp_gemm<<<2048, 256, 0, stream>>>(x, Wx, d_ws);
  rnn_scan<<<32, 256, 0, stream>>>(Wh, Wy, by, d_ws, (float*)d_out);
}

// Round 5
// 5017.154 us; speedup vs baseline: 1.8262x; 1.0417x over previous
//
#include <hip/hip_runtime.h>

typedef __bf16 bf16x8 __attribute__((ext_vector_type(8)));
typedef unsigned short ushort8_t __attribute__((ext_vector_type(8)));
typedef float f32x4 __attribute__((ext_vector_type(4)));
typedef unsigned int uint4_t __attribute__((ext_vector_type(4)));

#define MFMA16(a,b,c) __builtin_amdgcn_mfma_f32_16x16x32_bf16((a),(b),(c),0,0,0)

// B=512 T=1024 Din=128 H=512 Dout=128
// v5: register-budget-exact scan.
//  - xp_gemm: xp = x@Wx^T + (bx+bh), bf16, scan-ready layout in g_xp (512MB static).
//  - rnn_scan: 32 blocks x 256 thr (4 waves, 1 wave/SIMD -> 512 reg budget).
//    Wave owns 128 cols. Wh: kt0-7 AGPR (256), kt12-15 arch VGPR (128), kt8-11 LDS (128KB).
//    h [16][512] bf16 single-buffer in-place, swizzled; 2 barriers/step.
//    h-writes pair-packed via DPP quad_perm -> ds_write_b32, even lanes only.

__device__ unsigned short g_xp[(size_t)32 * 1024 * 256 * 32];  // 512MB bf16

__device__ __forceinline__ unsigned short f2bf(float f) {
  unsigned int u = __float_as_uint(f);
  u += 0x7FFFu + ((u >> 16) & 1u);  // RTNE
  return (unsigned short)(u >> 16);
}
__device__ __forceinline__ bf16x8 pack8v(float4 a, float4 b) {
  ushort8_t u;
  u[0] = f2bf(a.x); u[1] = f2bf(a.y); u[2] = f2bf(a.z); u[3] = f2bf(a.w);
  u[4] = f2bf(b.x); u[5] = f2bf(b.y); u[6] = f2bf(b.z); u[7] = f2bf(b.w);
  return __builtin_bit_cast(bf16x8, u);
}
__device__ __forceinline__ bf16x8 pack8p(const float* __restrict__ s) {
  return pack8v(*(const float4*)s, *(const float4*)(s + 4));
}

// ---- xp precompute: 2048 blocks (g 0..31, tc 0..63), 256 thr --------------
__global__ __launch_bounds__(256) void xp_gemm(const float* __restrict__ x,
                                               const float* __restrict__ Wx,
                                               const float* __restrict__ bx,
                                               const float* __restrict__ bh) {
  __shared__ alignas(16) char xs[65536];  // 16 t x [16 row][128 k] bf16, swizzled
  const int tid = threadIdx.x;
  const int w = tid >> 6, l = tid & 63, m = l & 15, kg = l >> 4;
  const int g = blockIdx.x & 31, tc = blockIdx.x >> 5;
  const int bb = g << 4, t0 = tc << 4;
  const int sw = (m & 7) << 4;

  // B-frags (Wx) + bias
  bf16x8 bwx[4][8];
  float bias[8];
#pragma unroll
  for (int cf = 0; cf < 8; ++cf) {
    const int c = w * 128 + cf * 16 + m;
    bias[cf] = bx[c] + bh[c];
#pragma unroll
    for (int kt = 0; kt < 4; ++kt)
      bwx[kt][cf] = pack8p(Wx + (size_t)c * 128 + kt * 32 + kg * 8);
  }

  // stage x slab: (b=16 rows) x (t=16) x 128 k f32 -> bf16 LDS
#pragma unroll
  for (int pass = 0; pass < 8; ++pass) {
    const int row = pass * 32 + (tid >> 3);
    const int mr = row >> 4, tr = row & 15;
    const float* src = x + ((size_t)(bb + mr) * 1024 + t0 + tr) * 128 + (tid & 7) * 16;
    const int wbase = tr * 4096 + mr * 256;
    const int swr = (mr & 7) << 4;
#pragma unroll
    for (int j = 0; j < 4; ++j) {
      float4 v = *(const float4*)(src + j * 4);
      unsigned lo = (unsigned)f2bf(v.x) | ((unsigned)f2bf(v.y) << 16);
      unsigned hi = (unsigned)f2bf(v.z) | ((unsigned)f2bf(v.w) << 16);
      unsigned* dst = (unsigned*)(xs + wbase + (((tid & 7) * 32 + j * 8) ^ swr));
      dst[0] = lo; dst[1] = hi;
    }
  }
  __syncthreads();

  const int xE = m * 256 + ((kg << 4) ^ sw);
  const int xO = xE ^ 64;

  for (int t = 0; t < 16; ++t) {
    f32x4 acc[8];
#pragma unroll
    for (int cf = 0; cf < 8; ++cf) acc[cf] = (f32x4){0.f, 0.f, 0.f, 0.f};
#pragma unroll
    for (int kt = 0; kt < 4; ++kt) {
      bf16x8 a = *(const bf16x8*)(xs + t * 4096 + ((kt >> 1) << 7) + ((kt & 1) ? xO : xE));
#pragma unroll
      for (int cf = 0; cf < 8; ++cf) acc[cf] = MFMA16(a, bwx[kt][cf], acc[cf]);
    }
    unsigned dw[16];
#pragma unroll
    for (int cf = 0; cf < 8; ++cf) {
      float p0 = acc[cf][0] + bias[cf], p1 = acc[cf][1] + bias[cf];
      float p2 = acc[cf][2] + bias[cf], p3 = acc[cf][3] + bias[cf];
      dw[cf * 2]     = (unsigned)f2bf(p0) | ((unsigned)f2bf(p1) << 16);
      dw[cf * 2 + 1] = (unsigned)f2bf(p2) | ((unsigned)f2bf(p3) << 16);
    }
    uint4_t* dst = (uint4_t*)(g_xp + ((size_t)((g * 1024) + (t0 + t)) * 256 + tid) * 32);
#pragma unroll
    for (int j = 0; j < 4; ++j)
      dst[j] = (uint4_t){dw[4 * j], dw[4 * j + 1], dw[4 * j + 2], dw[4 * j + 3]};
  }
}

// ---- scan: 32 blocks x 256 thr --------------------------------------------
__global__ __launch_bounds__(256, 1) void rnn_scan(
    const float* __restrict__ Wh, const float* __restrict__ Wy,
    const float* __restrict__ by, float* __restrict__ out) {
  __shared__ alignas(16) char h_lds[16384];   // [16 row][512 c] bf16, swizzled, in-place
  __shared__ alignas(16) char wb_lds[131072]; // Wh kt8..11 B-frags

  const int tid = threadIdx.x;
  const int w = tid >> 6, l = tid & 63, m = l & 15, kg = l >> 4;
  const int g = blockIdx.x, bb = g << 4;

  // stage wb_lds: each thread packs its own (w,l) slice of kt8..11
#pragma unroll
  for (int ktl = 0; ktl < 4; ++ktl)
#pragma unroll
    for (int cf = 0; cf < 8; ++cf) {
      const int c = w * 128 + cf * 16 + m;
      const int k = (8 + ktl) * 32 + kg * 8;
      *(bf16x8*)(wb_lds + ((w * 32 + ktl * 8 + cf) * 64 + l) * 16) =
          pack8p(Wh + (size_t)c * 512 + k);
    }

  // resident weights: kt0..7 (AGPR-class, MFMA-only use), kt12..15 (arch)
  bf16x8 bw[8][8];
  bf16x8 bw2[4][8];
#pragma unroll
  for (int cf = 0; cf < 8; ++cf) {
    const int c = w * 128 + cf * 16 + m;
#pragma unroll
    for (int kt = 0; kt < 8; ++kt)
      bw[kt][cf] = pack8p(Wh + (size_t)c * 512 + kt * 32 + kg * 8);
#pragma unroll
    for (int ktl = 0; ktl < 4; ++ktl)
      bw2[ktl][cf] = pack8p(Wh + (size_t)c * 512 + (12 + ktl) * 32 + kg * 8);
  }

  // A-read bases: elem (r,k) at r*1024 + ((k>>6)<<7) + ((2*(k&63)) ^ ((r&7)<<4))
  const int aE = m * 1024 + ((kg << 4) ^ ((m & 7) << 4));
  const int aO = aE ^ 64;
  const char* wbp = wb_lds + ((w * 32) * 64 + l) * 16;  // + (ktl*8+cf)*1024

  // zero h(0)
  {
    uint4_t z = {0, 0, 0, 0};
#pragma unroll
    for (int j = 0; j < 4; ++j) *(uint4_t*)(h_lds + tid * 64 + j * 16) = z;
  }

  const char* xpb = (const char*)(g_xp + ((size_t)g * 1024 * 256 + tid) * 32);
  uint4_t xq0, xq1, xq2, xq3;
  { const uint4_t* p = (const uint4_t*)xpb; xq0 = p[0]; xq1 = p[1]; xq2 = p[2]; xq3 = p[3]; }
  __syncthreads();

  for (int t = 0; t < 1024; ++t) {
    // prefetch xp(t+1)
    const int tn = (t < 1023) ? t + 1 : 1023;
    const uint4_t* pn = (const uint4_t*)(xpb + (size_t)tn * 16384);
    uint4_t nq0 = pn[0], nq1 = pn[1], nq2 = pn[2], nq3 = pn[3];

    // acc init from xp (bias included)
    f32x4 acc[8];
#pragma unroll
    for (int cf = 0; cf < 8; ++cf) {
      const uint4_t q = (cf < 2) ? xq0 : (cf < 4) ? xq1 : (cf < 6) ? xq2 : xq3;
      const unsigned dlo = q[(cf & 1) * 2], dhi = q[(cf & 1) * 2 + 1];
      acc[cf][0] = __uint_as_float(dlo << 16);
      acc[cf][1] = __uint_as_float(dlo & 0xffff0000u);
      acc[cf][2] = __uint_as_float(dhi << 16);
      acc[cf][3] = __uint_as_float(dhi & 0xffff0000u);
    }

    // kt0..7 from AGPR-resident
#pragma unroll
    for (int kt = 0; kt < 8; ++kt) {
      bf16x8 a = *(const bf16x8*)(h_lds + ((kt & 1) ? aO : aE) + ((kt >> 1) << 7));
#pragma unroll
      for (int cf = 0; cf < 8; ++cf) acc[cf] = MFMA16(a, bw[kt][cf], acc[cf]);
    }
    // kt8..11 from LDS
#pragma unroll
    for (int ktl = 0; ktl < 4; ++ktl) {
      const int kt = 8 + ktl;
      bf16x8 a = *(const bf16x8*)(h_lds + ((kt & 1) ? aO : aE) + ((kt >> 1) << 7));
#pragma unroll
      for (int cf = 0; cf < 8; ++cf) {
        bf16x8 b = *(const bf16x8*)(wbp + (ktl * 8 + cf) * 1024);
        acc[cf] = MFMA16(a, b, acc[cf]);
      }
    }
    // kt12..15 from arch-resident
#pragma unroll
    for (int ktl = 0; ktl < 4; ++ktl) {
      const int kt = 12 + ktl;
      bf16x8 a = *(const bf16x8*)(h_lds + ((kt & 1) ? aO : aE) + ((kt >> 1) << 7));
#pragma unroll
      for (int cf = 0; cf < 8; ++cf) acc[cf] = MFMA16(a, bw2[ktl][cf], acc[cf]);
    }

    __syncthreads();  // all reads of h(t) complete before in-place overwrite

    // tanh -> bf16; DPP pair (lanes m<->m^1 share k-adjacent cols) -> b32 writes
#pragma unroll
    for (int cf = 0; cf < 8; ++cf) {
      const int cblk = (w * 2 + (cf >> 2)) << 7;
      const int col2 = ((cf & 3) << 5) + 2 * m;
#pragma unroll
      for (int i = 0; i < 4; ++i) {
        float e = __expf(2.f * acc[cf][i]);
        float hv = 1.f - 2.f / (e + 1.f);  // tanh, saturates at +/-1
        unsigned u = (unsigned)f2bf(hv);
        unsigned nb = (unsigned)__builtin_amdgcn_mov_dpp((int)u, 0xB1, 0xF, 0xF, true);
        if (!(m & 1)) {
          const int r = kg * 4 + i;
          const int addr = r * 1024 + cblk + (col2 ^ ((r & 7) << 4));
          *(unsigned*)(h_lds + addr) = u | (nb << 16);
        }
      }
    }
    __syncthreads();
    xq0 = nq0; xq1 = nq1; xq2 = nq2; xq3 = nq3;
  }

  // epilogue: y = h(1024) @ Wy^T + by
  f32x4 y0 = {0, 0, 0, 0}, y1 = {0, 0, 0, 0};
  const int c0 = w * 32 + m, c1 = w * 32 + 16 + m;
#pragma unroll
  for (int kt = 0; kt < 16; ++kt) {
    bf16x8 a = *(const bf16x8*)(h_lds + ((kt & 1) ? aO : aE) + ((kt >> 1) << 7));
    y0 = MFMA16(a, pack8p(Wy + (size_t)c0 * 512 + kt * 32 + kg * 8), y0);
    y1 = MFMA16(a, pack8p(Wy + (size_t)c1 * 512 + kt * 32 + kg * 8), y1);
  }
  const float b0 = by[c0], b1 = by[c1];
#pragma unroll
  for (int i = 0; i < 4; ++i) {
    const int r = kg * 4 + i;
    out[(size_t)(bb + r) * 128 + c0] = y0[i] + b0;
    out[(size_t)(bb + r) * 128 + c1] = y1[i] + b1;
  }
}

extern "C" void kernel_launch(void* const* d_in, const int* in_sizes, int n_in,
                              void* d_out, int out_size, void* d_ws, size_t ws_size,
                              hipStream_t stream) {
  const float* x  = (const float*)d_in[0];
  const float* Wx = (const float*)d_in[1];
  const float* bx = (const float*)d_in[2];
  const float* Wh = (const float*)d_in[3];
  const float* bh = (const float*)d_in[4];
  const float* Wy = (const float*)d_in[5];
  const float* by = (const float*)d_in[6];

  xp_gemm<<<2048, 256, 0, stream>>>(x, Wx, bx, bh);
  rnn_scan<<<32, 256, 0, stream>>>(Wh, Wy, by, (float*)d_out);
}